// Round 16
// baseline (226.100 us; speedup 1.0000x reference)
//
#include <hip/hip_runtime.h>

#define NH 16
#define HD 64
#define TSEQ 2048
#define DMODEL 1024

typedef __attribute__((ext_vector_type(8))) short short8;
typedef __attribute__((ext_vector_type(4))) float f32x4;

static __device__ __forceinline__ unsigned short f2bf(float f) {
    unsigned u = __builtin_bit_cast(unsigned, f);
    u += 0x7FFF + ((u >> 16) & 1);
    return (unsigned short)(u >> 16);
}

// packed f32x2 -> bf16x2 (low = a, high = b), single VALU op
static __device__ __forceinline__ unsigned cvtpk(float a, float b) {
    unsigned r;
    asm("v_cvt_pk_bf16_f32 %0, %1, %2" : "=v"(r) : "v"(a), "v"(b));
    return r;
}

// ---------------- cast f32 -> bf16 (vectorized) ----------------
__global__ __launch_bounds__(256) void cast_f32_bf16(const float* __restrict__ src,
                                                     unsigned short* __restrict__ dst, int n4) {
    int i = blockIdx.x * 256 + threadIdx.x;
    if (i >= n4) return;
    float4 v = reinterpret_cast<const float4*>(src)[i];
    ushort4 o;
    o.x = f2bf(v.x); o.y = f2bf(v.y); o.z = f2bf(v.z); o.w = f2bf(v.w);
    reinterpret_cast<ushort4*>(dst)[i] = o;
}

__global__ __launch_bounds__(256) void cast_weights(const float* __restrict__ Wq,
                                                    const float* __restrict__ Wk,
                                                    const float* __restrict__ Wv,
                                                    const float* __restrict__ Wo,
                                                    unsigned short* __restrict__ dq,
                                                    unsigned short* __restrict__ dk,
                                                    unsigned short* __restrict__ dv,
                                                    unsigned short* __restrict__ dwo) {
    int g = blockIdx.x >> 10;
    int i = (blockIdx.x & 1023) * 256 + threadIdx.x;
    const float* s = (g == 0) ? Wq : (g == 1) ? Wk : (g == 2) ? Wv : Wo;
    unsigned short* d = (g == 0) ? dq : (g == 1) ? dk : (g == 2) ? dv : dwo;
    float4 v = reinterpret_cast<const float4*>(s)[i];
    ushort4 o;
    o.x = f2bf(v.x); o.y = f2bf(v.y); o.z = f2bf(v.z); o.w = f2bf(v.w);
    reinterpret_cast<ushort4*>(d)[i] = o;
}

// ============ 256x128 GEMM mainloop: 512 threads, 3-ring, counted vmcnt ============
// (unchanged from r12: 2 blocks/CU TLP + kt+2 prefetch + one barrier/K-tile
// with vmcnt(3))
static __device__ __forceinline__ void gemm256_mainloop(
    const unsigned short* __restrict__ A, const unsigned short* __restrict__ Bt,
    int m0, int n0, unsigned short* As, unsigned short* Bs, f32x4 acc[4][4]) {
    const int tid = threadIdx.x, lane = tid & 63, w = tid >> 6;
    const int wr = w >> 1, wc = w & 1;      // 4M x 2N
    const int lg = lane >> 4, ll = lane & 15;
    const int strow = tid >> 2;             // 0..127
    const int su = tid & 3;                 // 16B unit within 64B row
    const int rx = ll & 3;                  // read-side XOR (== row&3 of frag rows)

    const f32x4 zero = {0.f, 0.f, 0.f, 0.f};
#pragma unroll
    for (int i = 0; i < 4; i++)
#pragma unroll
        for (int j = 0; j < 4; j++) acc[i][j] = zero;

    auto stage = [&](int kt, int slot) {    // 3 loads/thread: 2 A + 1 B
#pragma unroll
        for (int s = 0; s < 2; ++s) {       // A rows 0..255
            int row = s * 128 + strow;
            int gcol = kt * 32 + ((su ^ (row & 3)) * 8);
            __builtin_amdgcn_global_load_lds(
                (const __attribute__((address_space(1))) void*)(A + (size_t)(m0 + row) * DMODEL + gcol),
                (__attribute__((address_space(3))) void*)(As + slot * 8192 + row * 32 + su * 8), 16, 0, 0);
        }
        {                                   // B rows 0..127
            int row = strow;
            int gcol = kt * 32 + ((su ^ (row & 3)) * 8);
            __builtin_amdgcn_global_load_lds(
                (const __attribute__((address_space(1))) void*)(Bt + (size_t)(n0 + row) * DMODEL + gcol),
                (__attribute__((address_space(3))) void*)(Bs + slot * 4096 + row * 32 + su * 8), 16, 0, 0);
        }
    };

    // prologue: tiles 0,1; wait tile0 (tile1's 3 loads stay in flight)
    stage(0, 0);
    stage(1, 1);
    asm volatile("s_waitcnt vmcnt(3)" ::: "memory");
    __builtin_amdgcn_s_barrier();
    __builtin_amdgcn_sched_barrier(0);

    int pb = 0;
#pragma unroll 1
    for (int kt = 0; kt < 32; ++kt) {
        short8 af[4], bf[4];
#pragma unroll
        for (int i = 0; i < 4; i++)
            af[i] = *(const short8*)(As + pb * 8192 + (wr * 64 + i * 16 + ll) * 32 + ((lg ^ rx) * 8));
#pragma unroll
        for (int j = 0; j < 4; j++)
            bf[j] = *(const short8*)(Bs + pb * 4096 + (wc * 64 + j * 16 + ll) * 32 + ((lg ^ rx) * 8));
        const int pn = (pb + 2 >= 3) ? (pb - 1) : (pb + 2);
        if (kt + 2 < 32) stage(kt + 2, pn);

        asm volatile("s_waitcnt lgkmcnt(0)" ::: "memory");
        __builtin_amdgcn_sched_barrier(0);
        __builtin_amdgcn_s_setprio(1);
#pragma unroll
        for (int i = 0; i < 4; i++)
#pragma unroll
            for (int j = 0; j < 4; j++)
                acc[i][j] = __builtin_amdgcn_mfma_f32_16x16x32_bf16(af[i], bf[j], acc[i][j], 0, 0, 0);
        __builtin_amdgcn_s_setprio(0);
        __builtin_amdgcn_sched_barrier(0);
        if (kt + 2 < 32) {
            asm volatile("s_waitcnt vmcnt(3)" ::: "memory");   // kt+1 landed; kt+2 in flight
        } else {
            asm volatile("s_waitcnt vmcnt(0)" ::: "memory");   // tail drain
        }
        __builtin_amdgcn_s_barrier();
        __builtin_amdgcn_sched_barrier(0);
        pb = (pb + 1 >= 3) ? 0 : (pb + 1);
    }
}

// ---------------- QKV projection ----------------
#define QSCALE 0.180336880f
__global__ __launch_bounds__(512) void gemm_qkv(const unsigned short* __restrict__ xb,
                                                const unsigned short* __restrict__ Wqb,
                                                const unsigned short* __restrict__ Wkb,
                                                const unsigned short* __restrict__ Wvb,
                                                unsigned short* __restrict__ Q,
                                                unsigned short* __restrict__ K,
                                                unsigned short* __restrict__ Vt) {
    __shared__ __attribute__((aligned(16))) unsigned short As[3 * 256 * 32];
    __shared__ __attribute__((aligned(16))) unsigned short Bs[3 * 128 * 32];
    const int m0 = blockIdx.x * 256;
    const int n0 = blockIdx.y * 128;
    const int z = blockIdx.z;
    const unsigned short* Bt = (z == 0) ? Wqb : ((z == 1) ? Wkb : Wvb);
    unsigned short* out = (z == 0) ? Q : ((z == 1) ? K : Vt);

    f32x4 acc[4][4];
    gemm256_mainloop(xb, Bt, m0, n0, As, Bs, acc);

    const int lane = threadIdx.x & 63, w = threadIdx.x >> 6;
    const int wr = w >> 1, wc = w & 1;
    const int lg = lane >> 4, ll = lane & 15;
    const float sc = (z == 0) ? QSCALE : 1.0f;
    if (z == 2) {
#pragma unroll
        for (int i = 0; i < 4; i++)
#pragma unroll
            for (int j = 0; j < 4; j++) {
                int row0 = m0 + wr * 64 + i * 16 + lg * 4;      // aligned to 4
                int col = n0 + wc * 64 + j * 16 + ll;
                int b = row0 >> 11, t0 = row0 & 2047;
                int h = col >> 6, d = col & 63;
                ushort4 v4;
                v4.x = f2bf(acc[i][j][0]); v4.y = f2bf(acc[i][j][1]);
                v4.z = f2bf(acc[i][j][2]); v4.w = f2bf(acc[i][j][3]);
                *(ushort4*)&Vt[(((size_t)(b * NH + h)) * HD + d) * TSEQ + t0] = v4;
            }
    } else {
#pragma unroll
        for (int i = 0; i < 4; i++)
#pragma unroll
            for (int j = 0; j < 4; j++)
#pragma unroll
                for (int r = 0; r < 4; r++) {
                    int row = m0 + wr * 64 + i * 16 + lg * 4 + r;   // b*2048 + t
                    int col = n0 + wc * 64 + j * 16 + ll;           // h*64 + d
                    int b = row >> 11, t = row & 2047;
                    int h = col >> 6, d = col & 63;
                    out[(((size_t)(b * NH + h)) * TSEQ + t) * HD + d] = f2bf(acc[i][j][r] * sc);
                }
    }
}

// ---------------- output projection ----------------
__global__ __launch_bounds__(512) void gemm_out(const unsigned short* __restrict__ ctx,
                                                const unsigned short* __restrict__ Wob,
                                                const float* __restrict__ bo,
                                                float* __restrict__ out) {
    __shared__ __attribute__((aligned(16))) unsigned short As[3 * 256 * 32];
    __shared__ __attribute__((aligned(16))) unsigned short Bs[3 * 128 * 32];
    const int m0 = blockIdx.x * 256;
    const int n0 = blockIdx.y * 128;

    f32x4 acc[4][4];
    gemm256_mainloop(ctx, Wob, m0, n0, As, Bs, acc);

    const int lane = threadIdx.x & 63, w = threadIdx.x >> 6;
    const int wr = w >> 1, wc = w & 1;
    const int lg = lane >> 4, ll = lane & 15;
#pragma unroll
    for (int i = 0; i < 4; i++)
#pragma unroll
        for (int j = 0; j < 4; j++) {
            int col = n0 + wc * 64 + j * 16 + ll;
            float bias = bo[col];
#pragma unroll
            for (int r = 0; r < 4; r++) {
                int row = m0 + wr * 64 + i * 16 + lg * 4 + r;
                out[(size_t)row * DMODEL + col] = acc[i][j][r] + bias;
            }
        }
}

// ---------------- flash attention (causal), NO K/V STAGING, barrier-free ----------------
// r16: K/V MFMA fragments depend only on (ll,lg) — identical across all 8
// waves — so each wave loads them DIRECTLY from global (coalesced b128,
// served by L1/L2; K+V per head = 512KB << 4MB L2). This deletes the
// staging ds_writes, all K/V ds_reads (~2/3 of the DS-pipe load), and EVERY
// in-loop block barrier (Common-mistake #7 / m169). Waves run independently
// with exact causal trip counts (no skipped iterations, wave-level
// granularity). LDS = P buffer only (36,864 B). V loads issued before
// softmax so their latency hides under QK^T+softmax VALU.
__global__ __launch_bounds__(512) void attn(const unsigned short* __restrict__ Qg,
                                            const unsigned short* __restrict__ Kg,
                                            const unsigned short* __restrict__ Vg,
                                            unsigned short* __restrict__ ctx) {
    __shared__ __attribute__((aligned(16))) unsigned short Pl[256][72];

    const int tid = threadIdx.x, lane = tid & 63, w = tid >> 6;   // w = 0..7
    const int wq = w * 32;            // block-local P-slice row
    const int lg = lane >> 4;
    const int ll = lane & 15;
    const int bh = blockIdx.x;
    const int q0 = (gridDim.y - 1 - blockIdx.y) * 256;   // heavy tiles first
    const int qbase = q0 + wq;        // this wave's 32 q-rows
    const unsigned short* Qh = Qg + (size_t)bh * TSEQ * HD;
    const unsigned short* Kh = Kg + (size_t)bh * TSEQ * HD;
    const unsigned short* Vh = Vg + (size_t)bh * HD * TSEQ;

    short8 qf[2][2];
#pragma unroll
    for (int rb = 0; rb < 2; rb++)
#pragma unroll
        for (int ks = 0; ks < 2; ks++)
            qf[rb][ks] = *(const short8*)(Qh + (size_t)(qbase + rb * 16 + ll) * HD + ks * 32 + lg * 8);

    float mrun[2] = {-1e30f, -1e30f}, lrun[2] = {0.f, 0.f};
    const f32x4 zerov = {0.f, 0.f, 0.f, 0.f};
    f32x4 o_t[2][4];
#pragma unroll
    for (int rb = 0; rb < 2; rb++)
#pragma unroll
        for (int db = 0; db < 4; db++) o_t[rb][db] = zerov;

    const int nkv = (qbase + 31) / 64 + 1;   // exact causal range for this wave
    for (int kt = 0; kt < nkv; kt++) {
        const int kv0 = kt * 64;

        // K fragments direct from global (rows kv0+cb*16+ll, coalesced 2KB/instr)
        short8 af0[4], af1[4];
#pragma unroll
        for (int cb = 0; cb < 4; cb++) {
            af0[cb] = *(const short8*)(Kh + (size_t)(kv0 + cb * 16 + ll) * HD + lg * 8);
            af1[cb] = *(const short8*)(Kh + (size_t)(kv0 + cb * 16 + ll) * HD + 32 + lg * 8);
        }
        // V fragments direct from global — issued NOW, consumed after softmax
        short8 va[2][4];
#pragma unroll
        for (int ks = 0; ks < 2; ks++)
#pragma unroll
            for (int db = 0; db < 4; db++)
                va[ks][db] = *(const short8*)(Vh + (size_t)(db * 16 + ll) * TSEQ + kv0 + ks * 32 + lg * 8);

        f32x4 st[2][4];
#pragma unroll
        for (int rb = 0; rb < 2; rb++)
#pragma unroll
            for (int cb = 0; cb < 4; cb++)
                st[rb][cb] = __builtin_amdgcn_mfma_f32_16x16x32_bf16(af0[cb], qf[rb][0], zerov, 0, 0, 0);
#pragma unroll
        for (int rb = 0; rb < 2; rb++)
#pragma unroll
            for (int cb = 0; cb < 4; cb++)
                st[rb][cb] = __builtin_amdgcn_mfma_f32_16x16x32_bf16(af1[cb], qf[rb][1], st[rb][cb], 0, 0, 0);

        if (kv0 + 63 > qbase) {   // diagonal-crossing tile
#pragma unroll
            for (int rb = 0; rb < 2; rb++)
#pragma unroll
                for (int cb = 0; cb < 4; cb++)
#pragma unroll
                    for (int r = 0; r < 4; r++) {
                        int kvl = cb * 16 + lg * 4 + r;
                        int ql = rb * 16 + ll;
                        if (kv0 + kvl > qbase + ql) st[rb][cb][r] = -1e30f;
                    }
        }

        float mx[2];
#pragma unroll
        for (int rb = 0; rb < 2; rb++) {
            float a0 = fmaxf(fmaxf(st[rb][0][0], st[rb][0][1]), fmaxf(st[rb][0][2], st[rb][0][3]));
            float a1 = fmaxf(fmaxf(st[rb][1][0], st[rb][1][1]), fmaxf(st[rb][1][2], st[rb][1][3]));
            float a2 = fmaxf(fmaxf(st[rb][2][0], st[rb][2][1]), fmaxf(st[rb][2][2], st[rb][2][3]));
            float a3 = fmaxf(fmaxf(st[rb][3][0], st[rb][3][1]), fmaxf(st[rb][3][2], st[rb][3][3]));
            float m = fmaxf(fmaxf(a0, a1), fmaxf(a2, a3));
            m = fmaxf(m, __shfl_xor(m, 16));
            m = fmaxf(m, __shfl_xor(m, 32));
            mx[rb] = m;
        }
        float need = fmaxf(mx[0] - mrun[0], mx[1] - mrun[1]);
        if (__any(need > 8.f)) {
#pragma unroll
            for (int rb = 0; rb < 2; rb++) {
                float mold = mrun[rb];
                float mn = fmaxf(mold, mx[rb]);
                float rs = __builtin_amdgcn_exp2f(mold - mn);
                mrun[rb] = mn;
                lrun[rb] *= rs;
#pragma unroll
                for (int db = 0; db < 4; db++)
#pragma unroll
                    for (int r = 0; r < 4; r++) o_t[rb][db][r] *= rs;
            }
        }
#pragma unroll
        for (int rb = 0; rb < 2; rb++) {
            float sum = 0.f;
#pragma unroll
            for (int cb = 0; cb < 4; cb++) {
                float p0 = __builtin_amdgcn_exp2f(st[rb][cb][0] - mrun[rb]);
                float p1 = __builtin_amdgcn_exp2f(st[rb][cb][1] - mrun[rb]);
                float p2 = __builtin_amdgcn_exp2f(st[rb][cb][2] - mrun[rb]);
                float p3 = __builtin_amdgcn_exp2f(st[rb][cb][3] - mrun[rb]);
                sum += (p0 + p1) + (p2 + p3);
                uint2 pw;
                pw.x = cvtpk(p0, p1);
                pw.y = cvtpk(p2, p3);
                *(uint2*)&Pl[wq + rb * 16 + ll][cb * 16 + lg * 4] = pw;
            }
            sum += __shfl_xor(sum, 16);
            sum += __shfl_xor(sum, 32);
            lrun[rb] += sum;
        }
        // wave-private P: drain this wave's LDS ops only (no block barrier!)
        asm volatile("s_waitcnt lgkmcnt(0)" ::: "memory");
        __builtin_amdgcn_sched_barrier(0);

#pragma unroll
        for (int ks = 0; ks < 2; ks++) {
            short8 pa[2];
#pragma unroll
            for (int rb = 0; rb < 2; rb++)
                pa[rb] = *(const short8*)&Pl[wq + rb * 16 + ll][ks * 32 + lg * 8];
#pragma unroll
            for (int rb = 0; rb < 2; rb++)
#pragma unroll
                for (int db = 0; db < 4; db++)
                    o_t[rb][db] = __builtin_amdgcn_mfma_f32_16x16x32_bf16(va[ks][db], pa[rb], o_t[rb][db], 0, 0, 0);
        }
    }

    const int b = bh >> 4, h = bh & 15;
#pragma unroll
    for (int rb = 0; rb < 2; rb++) {
        float linv = 1.f / lrun[rb];
#pragma unroll
        for (int db = 0; db < 4; db++) {
            uint2 pw;
            pw.x = cvtpk(o_t[rb][db][0] * linv, o_t[rb][db][1] * linv);
            pw.y = cvtpk(o_t[rb][db][2] * linv, o_t[rb][db][3] * linv);
            *(uint2*)&Pl[wq + rb * 16 + ll][db * 16 + lg * 4] = pw;
        }
    }
    asm volatile("s_waitcnt lgkmcnt(0)" ::: "memory");
    __builtin_amdgcn_sched_barrier(0);
#pragma unroll
    for (int rb = 0; rb < 2; rb++)
#pragma unroll
        for (int half = 0; half < 2; half++) {
            short8 v = *(const short8*)&Pl[wq + rb * 16 + ll][half * 32 + lg * 8];
            size_t row = (size_t)(b * TSEQ + qbase + rb * 16 + ll);
            *(short8*)(ctx + (row * NH + h) * HD + half * 32 + lg * 8) = v;
        }
}

extern "C" void kernel_launch(void* const* d_in, const int* in_sizes, int n_in,
                              void* d_out, int out_size, void* d_ws, size_t ws_size,
                              hipStream_t stream) {
    const float* x  = (const float*)d_in[0];
    const float* Wq = (const float*)d_in[1];
    const float* Wk = (const float*)d_in[2];
    const float* Wv = (const float*)d_in[3];
    const float* Wo = (const float*)d_in[4];
    const float* bo = (const float*)d_in[5];
    float* out = (float*)d_out;

    char* ws = (char*)d_ws;
    unsigned short* xb   = (unsigned short*)(ws);             // 16,777,216 B
    unsigned short* Wqb  = (unsigned short*)(ws + 16777216);
    unsigned short* Wkb  = (unsigned short*)(ws + 18874368);
    unsigned short* Wvb  = (unsigned short*)(ws + 20971520);
    unsigned short* Wob  = (unsigned short*)(ws + 23068672);
    unsigned short* Qb   = (unsigned short*)(ws + 25165824);  // [B,H,T,hd] bf16 (pre-scaled)
    unsigned short* Kb   = (unsigned short*)(ws + 41943040);  // [B,H,T,hd]
    unsigned short* Vtb  = (unsigned short*)(ws + 58720256);  // [B,H,hd,T]
    unsigned short* ctxb = (unsigned short*)(ws + 75497472);  // [B,T,H,hd]

    cast_f32_bf16<<<8192, 256, 0, stream>>>(x, xb, 2097152);
    cast_weights<<<4096, 256, 0, stream>>>(Wq, Wk, Wv, Wo, Wqb, Wkb, Wvb, Wob);

    gemm_qkv<<<dim3(32, 8, 3), 512, 0, stream>>>(xb, Wqb, Wkb, Wvb, Qb, Kb, Vtb);
    attn<<<dim3(64, 8), 512, 0, stream>>>(Qb, Kb, Vtb, ctxb);
    gemm_out<<<dim3(32, 8), 512, 0, stream>>>(ctxb, Wob, bo, out);
}

// Round 17
// 174.190 us; speedup vs baseline: 1.2980x; 1.2980x over previous
//
#include <hip/hip_runtime.h>

#define NH 16
#define HD 64
#define TSEQ 2048
#define DMODEL 1024

typedef __attribute__((ext_vector_type(8))) short short8;
typedef __attribute__((ext_vector_type(4))) float f32x4;

static __device__ __forceinline__ unsigned short f2bf(float f) {
    unsigned u = __builtin_bit_cast(unsigned, f);
    u += 0x7FFF + ((u >> 16) & 1);
    return (unsigned short)(u >> 16);
}

// packed f32x2 -> bf16x2 (low = a, high = b), single VALU op
static __device__ __forceinline__ unsigned cvtpk(float a, float b) {
    unsigned r;
    asm("v_cvt_pk_bf16_f32 %0, %1, %2" : "=v"(r) : "v"(a), "v"(b));
    return r;
}

// ---------------- cast f32 -> bf16 (vectorized) ----------------
__global__ __launch_bounds__(256) void cast_f32_bf16(const float* __restrict__ src,
                                                     unsigned short* __restrict__ dst, int n4) {
    int i = blockIdx.x * 256 + threadIdx.x;
    if (i >= n4) return;
    float4 v = reinterpret_cast<const float4*>(src)[i];
    ushort4 o;
    o.x = f2bf(v.x); o.y = f2bf(v.y); o.z = f2bf(v.z); o.w = f2bf(v.w);
    reinterpret_cast<ushort4*>(dst)[i] = o;
}

__global__ __launch_bounds__(256) void cast_weights(const float* __restrict__ Wq,
                                                    const float* __restrict__ Wk,
                                                    const float* __restrict__ Wv,
                                                    const float* __restrict__ Wo,
                                                    unsigned short* __restrict__ dq,
                                                    unsigned short* __restrict__ dk,
                                                    unsigned short* __restrict__ dv,
                                                    unsigned short* __restrict__ dwo) {
    int g = blockIdx.x >> 10;
    int i = (blockIdx.x & 1023) * 256 + threadIdx.x;
    const float* s = (g == 0) ? Wq : (g == 1) ? Wk : (g == 2) ? Wv : Wo;
    unsigned short* d = (g == 0) ? dq : (g == 1) ? dk : (g == 2) ? dv : dwo;
    float4 v = reinterpret_cast<const float4*>(s)[i];
    ushort4 o;
    o.x = f2bf(v.x); o.y = f2bf(v.y); o.z = f2bf(v.z); o.w = f2bf(v.w);
    reinterpret_cast<ushort4*>(d)[i] = o;
}

// ============ 128x128 GEMM mainloop: 512 threads, 3-ring, counted vmcnt ============
// r17: BM 256->128 for GRID PACKING at 2 blocks/CU capacity: qkv grid
// 64x8x3=1536 = 3 full rounds of 512 resident (r12's 768 = 1.5 rounds ->
// half-idle tail); gemm_out grid 64x8=512 = exactly 2/CU (was 256 = 1/CU,
// no TLP). Same proven mechanics as r12: 3-deep ring, kt+2 prefetch, ONE
// barrier + counted vmcnt(2) per K-tile, setprio MFMA cluster, row&3 XOR
// swizzle both-sides. 8 waves as 2M x 4N, wave tile 64x32 (acc 4x2).
// LDS: A 3x[128][32] (24KB) + B 3x[128][32] (24KB) = 48KB -> 2 blocks/CU.
static __device__ __forceinline__ void gemm128_mainloop(
    const unsigned short* __restrict__ A, const unsigned short* __restrict__ Bt,
    int m0, int n0, unsigned short* As, unsigned short* Bs, f32x4 acc[4][2]) {
    const int tid = threadIdx.x, lane = tid & 63, w = tid >> 6;
    const int wr = w >> 2, wc = w & 3;      // 2M x 4N
    const int lg = lane >> 4, ll = lane & 15;
    const int strow = tid >> 2;             // 0..127
    const int su = tid & 3;                 // 16B unit within 64B row
    const int rx = ll & 3;                  // read-side XOR (== row&3 of frag rows)

    const f32x4 zero = {0.f, 0.f, 0.f, 0.f};
#pragma unroll
    for (int i = 0; i < 4; i++)
#pragma unroll
        for (int j = 0; j < 2; j++) acc[i][j] = zero;

    auto stage = [&](int kt, int slot) {    // 2 loads/thread: 1 A + 1 B
        int gcol = kt * 32 + ((su ^ (strow & 3)) * 8);
        __builtin_amdgcn_global_load_lds(
            (const __attribute__((address_space(1))) void*)(A + (size_t)(m0 + strow) * DMODEL + gcol),
            (__attribute__((address_space(3))) void*)(As + slot * 4096 + strow * 32 + su * 8), 16, 0, 0);
        __builtin_amdgcn_global_load_lds(
            (const __attribute__((address_space(1))) void*)(Bt + (size_t)(n0 + strow) * DMODEL + gcol),
            (__attribute__((address_space(3))) void*)(Bs + slot * 4096 + strow * 32 + su * 8), 16, 0, 0);
    };

    // prologue: tiles 0,1; wait tile0 (tile1's 2 loads stay in flight)
    stage(0, 0);
    stage(1, 1);
    asm volatile("s_waitcnt vmcnt(2)" ::: "memory");
    __builtin_amdgcn_s_barrier();
    __builtin_amdgcn_sched_barrier(0);

    int pb = 0;
#pragma unroll 1
    for (int kt = 0; kt < 32; ++kt) {
        short8 af[4], bf[2];
#pragma unroll
        for (int i = 0; i < 4; i++)
            af[i] = *(const short8*)(As + pb * 4096 + (wr * 64 + i * 16 + ll) * 32 + ((lg ^ rx) * 8));
#pragma unroll
        for (int j = 0; j < 2; j++)
            bf[j] = *(const short8*)(Bs + pb * 4096 + (wc * 32 + j * 16 + ll) * 32 + ((lg ^ rx) * 8));
        const int pn = (pb + 2 >= 3) ? (pb - 1) : (pb + 2);
        if (kt + 2 < 32) stage(kt + 2, pn);

        asm volatile("s_waitcnt lgkmcnt(0)" ::: "memory");
        __builtin_amdgcn_sched_barrier(0);
        __builtin_amdgcn_s_setprio(1);
#pragma unroll
        for (int i = 0; i < 4; i++)
#pragma unroll
            for (int j = 0; j < 2; j++)
                acc[i][j] = __builtin_amdgcn_mfma_f32_16x16x32_bf16(af[i], bf[j], acc[i][j], 0, 0, 0);
        __builtin_amdgcn_s_setprio(0);
        __builtin_amdgcn_sched_barrier(0);
        if (kt + 2 < 32) {
            asm volatile("s_waitcnt vmcnt(2)" ::: "memory");   // kt+1 landed; kt+2 in flight
        } else {
            asm volatile("s_waitcnt vmcnt(0)" ::: "memory");   // tail drain
        }
        __builtin_amdgcn_s_barrier();
        __builtin_amdgcn_sched_barrier(0);
        pb = (pb + 1 >= 3) ? 0 : (pb + 1);
    }
}

// ---------------- QKV projection ----------------
#define QSCALE 0.180336880f
__global__ __launch_bounds__(512) void gemm_qkv(const unsigned short* __restrict__ xb,
                                                const unsigned short* __restrict__ Wqb,
                                                const unsigned short* __restrict__ Wkb,
                                                const unsigned short* __restrict__ Wvb,
                                                unsigned short* __restrict__ Q,
                                                unsigned short* __restrict__ K,
                                                unsigned short* __restrict__ Vt) {
    __shared__ __attribute__((aligned(16))) unsigned short As[3 * 128 * 32];
    __shared__ __attribute__((aligned(16))) unsigned short Bs[3 * 128 * 32];
    const int m0 = blockIdx.x * 128;
    const int n0 = blockIdx.y * 128;
    const int z = blockIdx.z;
    const unsigned short* Bt = (z == 0) ? Wqb : ((z == 1) ? Wkb : Wvb);
    unsigned short* out = (z == 0) ? Q : ((z == 1) ? K : Vt);

    f32x4 acc[4][2];
    gemm128_mainloop(xb, Bt, m0, n0, As, Bs, acc);

    const int lane = threadIdx.x & 63, w = threadIdx.x >> 6;
    const int wr = w >> 2, wc = w & 3;
    const int lg = lane >> 4, ll = lane & 15;
    const float sc = (z == 0) ? QSCALE : 1.0f;
    if (z == 2) {
        // Vt[(b*NH+h)*HD+d][t]: 4 consecutive r = 4 consecutive t -> ushort4
#pragma unroll
        for (int i = 0; i < 4; i++)
#pragma unroll
            for (int j = 0; j < 2; j++) {
                int row0 = m0 + wr * 64 + i * 16 + lg * 4;      // aligned to 4
                int col = n0 + wc * 32 + j * 16 + ll;
                int b = row0 >> 11, t0 = row0 & 2047;
                int h = col >> 6, d = col & 63;
                ushort4 v4;
                v4.x = f2bf(acc[i][j][0]); v4.y = f2bf(acc[i][j][1]);
                v4.z = f2bf(acc[i][j][2]); v4.w = f2bf(acc[i][j][3]);
                *(ushort4*)&Vt[(((size_t)(b * NH + h)) * HD + d) * TSEQ + t0] = v4;
            }
    } else {
#pragma unroll
        for (int i = 0; i < 4; i++)
#pragma unroll
            for (int j = 0; j < 2; j++)
#pragma unroll
                for (int r = 0; r < 4; r++) {
                    int row = m0 + wr * 64 + i * 16 + lg * 4 + r;   // b*2048 + t
                    int col = n0 + wc * 32 + j * 16 + ll;           // h*64 + d
                    int b = row >> 11, t = row & 2047;
                    int h = col >> 6, d = col & 63;
                    out[(((size_t)(b * NH + h)) * TSEQ + t) * HD + d] = f2bf(acc[i][j][r] * sc);
                }
    }
}

// ---------------- output projection ----------------
__global__ __launch_bounds__(512) void gemm_out(const unsigned short* __restrict__ ctx,
                                                const unsigned short* __restrict__ Wob,
                                                const float* __restrict__ bo,
                                                float* __restrict__ out) {
    __shared__ __attribute__((aligned(16))) unsigned short As[3 * 128 * 32];
    __shared__ __attribute__((aligned(16))) unsigned short Bs[3 * 128 * 32];
    const int m0 = blockIdx.x * 128;
    const int n0 = blockIdx.y * 128;

    f32x4 acc[4][2];
    gemm128_mainloop(ctx, Wob, m0, n0, As, Bs, acc);

    const int lane = threadIdx.x & 63, w = threadIdx.x >> 6;
    const int wr = w >> 2, wc = w & 3;
    const int lg = lane >> 4, ll = lane & 15;
#pragma unroll
    for (int i = 0; i < 4; i++)
#pragma unroll
        for (int j = 0; j < 2; j++) {
            int col = n0 + wc * 32 + j * 16 + ll;
            float bias = bo[col];
#pragma unroll
            for (int r = 0; r < 4; r++) {
                int row = m0 + wr * 64 + i * 16 + lg * 4 + r;
                out[(size_t)row * DMODEL + col] = acc[i][j][r] + bias;
            }
        }
}

// ---------------- flash attention (causal), Q-tile 256, KV-tile 64, 8 waves ----------------
// r12 structure verbatim (72.0 us — best measured; r13/r14/r15/r16 variants
// all falsified): single K/V buffer, 2 barriers/tile, reg-staged prefetch,
// S^T via mfma(K,Q), in-register softmax + 2 shfl, cvt_pk P-pack,
// O^T = mfma(Vt,P), per-wave skip of masked tiles, LPT order.
__global__ __launch_bounds__(512) void attn(const unsigned short* __restrict__ Qg,
                                            const unsigned short* __restrict__ Kg,
                                            const unsigned short* __restrict__ Vg,
                                            unsigned short* __restrict__ ctx) {
    __shared__ __attribute__((aligned(16))) unsigned short Ks[64][72];
    __shared__ __attribute__((aligned(16))) unsigned short Vs[64][72];
    __shared__ __attribute__((aligned(16))) unsigned short Pl[256][76];

    const int tid = threadIdx.x, lane = tid & 63, w = tid >> 6;   // w = 0..7
    const int wq = w * 32;
    const int lg = lane >> 4;
    const int ll = lane & 15;
    const int bh = blockIdx.x;
    const int q0 = (gridDim.y - 1 - blockIdx.y) * 256;   // heavy tiles first (LPT)
    const unsigned short* Qh = Qg + (size_t)bh * TSEQ * HD;
    const unsigned short* Kh = Kg + (size_t)bh * TSEQ * HD;
    const unsigned short* Vh = Vg + (size_t)bh * HD * TSEQ;

    short8 qf[2][2];
#pragma unroll
    for (int rb = 0; rb < 2; rb++)
#pragma unroll
        for (int ks = 0; ks < 2; ks++)
            qf[rb][ks] = *(const short8*)(Qh + (size_t)(q0 + wq + rb * 16 + ll) * HD + ks * 32 + lg * 8);

    float mrun[2] = {-1e30f, -1e30f}, lrun[2] = {0.f, 0.f};
    const f32x4 zerov = {0.f, 0.f, 0.f, 0.f};
    f32x4 o_t[2][4];
#pragma unroll
    for (int rb = 0; rb < 2; rb++)
#pragma unroll
        for (int db = 0; db < 4; db++) o_t[rb][db] = zerov;

    const int sr = tid >> 3;           // 0..63
    const int sc = (tid & 7) * 8;      // 0..56
    short8 kreg, vreg;
    kreg = *(const short8*)(Kh + (size_t)sr * HD + sc);
    vreg = *(const short8*)(Vh + (size_t)sr * TSEQ + sc);

    const int nkv = q0 / 64 + 4;
    for (int kt = 0; kt < nkv; kt++) {
        const int kv0 = kt * 64;
        __builtin_amdgcn_s_barrier();
        __builtin_amdgcn_sched_barrier(0);
        *(short8*)&Ks[sr][sc] = kreg;
        *(short8*)&Vs[sr][sc] = vreg;
        if (kt + 1 < nkv) {
            const int nv0 = kv0 + 64;
            kreg = *(const short8*)(Kh + (size_t)(nv0 + sr) * HD + sc);
            vreg = *(const short8*)(Vh + (size_t)sr * TSEQ + nv0 + sc);
        }
        __builtin_amdgcn_sched_barrier(0);
        asm volatile("s_waitcnt lgkmcnt(0)" ::: "memory");
        __builtin_amdgcn_s_barrier();
        __builtin_amdgcn_sched_barrier(0);

        if (kv0 > q0 + wq + 31) continue;   // fully masked for this wave

        short8 af0[4], af1[4];
#pragma unroll
        for (int cb = 0; cb < 4; cb++) {
            af0[cb] = *(const short8*)&Ks[cb * 16 + ll][lg * 8];
            af1[cb] = *(const short8*)&Ks[cb * 16 + ll][32 + lg * 8];
        }
        f32x4 st[2][4];
#pragma unroll
        for (int rb = 0; rb < 2; rb++)
#pragma unroll
            for (int cb = 0; cb < 4; cb++)
                st[rb][cb] = __builtin_amdgcn_mfma_f32_16x16x32_bf16(af0[cb], qf[rb][0], zerov, 0, 0, 0);
#pragma unroll
        for (int rb = 0; rb < 2; rb++)
#pragma unroll
            for (int cb = 0; cb < 4; cb++)
                st[rb][cb] = __builtin_amdgcn_mfma_f32_16x16x32_bf16(af1[cb], qf[rb][1], st[rb][cb], 0, 0, 0);

        if (kv0 + 63 > q0 + wq) {
#pragma unroll
            for (int rb = 0; rb < 2; rb++)
#pragma unroll
                for (int cb = 0; cb < 4; cb++)
#pragma unroll
                    for (int r = 0; r < 4; r++) {
                        int kvl = cb * 16 + lg * 4 + r;
                        int ql = wq + rb * 16 + ll;
                        if (kv0 + kvl > q0 + ql) st[rb][cb][r] = -1e30f;
                    }
        }

        float mx[2];
#pragma unroll
        for (int rb = 0; rb < 2; rb++) {
            float a0 = fmaxf(fmaxf(st[rb][0][0], st[rb][0][1]), fmaxf(st[rb][0][2], st[rb][0][3]));
            float a1 = fmaxf(fmaxf(st[rb][1][0], st[rb][1][1]), fmaxf(st[rb][1][2], st[rb][1][3]));
            float a2 = fmaxf(fmaxf(st[rb][2][0], st[rb][2][1]), fmaxf(st[rb][2][2], st[rb][2][3]));
            float a3 = fmaxf(fmaxf(st[rb][3][0], st[rb][3][1]), fmaxf(st[rb][3][2], st[rb][3][3]));
            float m = fmaxf(fmaxf(a0, a1), fmaxf(a2, a3));
            m = fmaxf(m, __shfl_xor(m, 16));
            m = fmaxf(m, __shfl_xor(m, 32));
            mx[rb] = m;
        }
        float need = fmaxf(mx[0] - mrun[0], mx[1] - mrun[1]);
        if (__any(need > 8.f)) {
#pragma unroll
            for (int rb = 0; rb < 2; rb++) {
                float mold = mrun[rb];
                float mn = fmaxf(mold, mx[rb]);
                float rs = __builtin_amdgcn_exp2f(mold - mn);
                mrun[rb] = mn;
                lrun[rb] *= rs;
#pragma unroll
                for (int db = 0; db < 4; db++)
#pragma unroll
                    for (int r = 0; r < 4; r++) o_t[rb][db][r] *= rs;
            }
        }
#pragma unroll
        for (int rb = 0; rb < 2; rb++) {
            float sum = 0.f;
#pragma unroll
            for (int cb = 0; cb < 4; cb++) {
                float p0 = __builtin_amdgcn_exp2f(st[rb][cb][0] - mrun[rb]);
                float p1 = __builtin_amdgcn_exp2f(st[rb][cb][1] - mrun[rb]);
                float p2 = __builtin_amdgcn_exp2f(st[rb][cb][2] - mrun[rb]);
                float p3 = __builtin_amdgcn_exp2f(st[rb][cb][3] - mrun[rb]);
                sum += (p0 + p1) + (p2 + p3);
                uint2 pw;
                pw.x = cvtpk(p0, p1);
                pw.y = cvtpk(p2, p3);
                *(uint2*)&Pl[wq + rb * 16 + ll][cb * 16 + lg * 4] = pw;
            }
            sum += __shfl_xor(sum, 16);
            sum += __shfl_xor(sum, 32);
            lrun[rb] += sum;
        }
        asm volatile("s_waitcnt lgkmcnt(0)" ::: "memory");
        __builtin_amdgcn_sched_barrier(0);

#pragma unroll
        for (int ks = 0; ks < 2; ks++) {
            short8 pa[2], va[4];
#pragma unroll
            for (int rb = 0; rb < 2; rb++)
                pa[rb] = *(const short8*)&Pl[wq + rb * 16 + ll][ks * 32 + lg * 8];
#pragma unroll
            for (int db = 0; db < 4; db++)
                va[db] = *(const short8*)&Vs[db * 16 + ll][ks * 32 + lg * 8];
#pragma unroll
            for (int rb = 0; rb < 2; rb++)
#pragma unroll
                for (int db = 0; db < 4; db++)
                    o_t[rb][db] = __builtin_amdgcn_mfma_f32_16x16x32_bf16(va[db], pa[rb], o_t[rb][db], 0, 0, 0);
        }
    }

    const int b = bh >> 4, h = bh & 15;
#pragma unroll
    for (int rb = 0; rb < 2; rb++) {
        float linv = 1.f / lrun[rb];
#pragma unroll
        for (int db = 0; db < 4; db++) {
            uint2 pw;
            pw.x = cvtpk(o_t[rb][db][0] * linv, o_t[rb][db][1] * linv);
            pw.y = cvtpk(o_t[rb][db][2] * linv, o_t[rb][db][3] * linv);
            *(uint2*)&Pl[wq + rb * 16 + ll][db * 16 + lg * 4] = pw;
        }
    }
    asm volatile("s_waitcnt lgkmcnt(0)" ::: "memory");
    __builtin_amdgcn_sched_barrier(0);
#pragma unroll
    for (int rb = 0; rb < 2; rb++)
#pragma unroll
        for (int half = 0; half < 2; half++) {
            short8 v = *(const short8*)&Pl[wq + rb * 16 + ll][half * 32 + lg * 8];
            size_t row = (size_t)(b * TSEQ + q0 + wq + rb * 16 + ll);
            *(short8*)(ctx + (row * NH + h) * HD + half * 32 + lg * 8) = v;
        }
}

extern "C" void kernel_launch(void* const* d_in, const int* in_sizes, int n_in,
                              void* d_out, int out_size, void* d_ws, size_t ws_size,
                              hipStream_t stream) {
    const float* x  = (const float*)d_in[0];
    const float* Wq = (const float*)d_in[1];
    const float* Wk = (const float*)d_in[2];
    const float* Wv = (const float*)d_in[3];
    const float* Wo = (const float*)d_in[4];
    const float* bo = (const float*)d_in[5];
    float* out = (float*)d_out;

    char* ws = (char*)d_ws;
    unsigned short* xb   = (unsigned short*)(ws);             // 16,777,216 B
    unsigned short* Wqb  = (unsigned short*)(ws + 16777216);
    unsigned short* Wkb  = (unsigned short*)(ws + 18874368);
    unsigned short* Wvb  = (unsigned short*)(ws + 20971520);
    unsigned short* Wob  = (unsigned short*)(ws + 23068672);
    unsigned short* Qb   = (unsigned short*)(ws + 25165824);  // [B,H,T,hd] bf16 (pre-scaled)
    unsigned short* Kb   = (unsigned short*)(ws + 41943040);  // [B,H,T,hd]
    unsigned short* Vtb  = (unsigned short*)(ws + 58720256);  // [B,H,hd,T]
    unsigned short* ctxb = (unsigned short*)(ws + 75497472);  // [B,T,H,hd]

    cast_f32_bf16<<<8192, 256, 0, stream>>>(x, xb, 2097152);
    cast_weights<<<4096, 256, 0, stream>>>(Wq, Wk, Wv, Wo, Wqb, Wkb, Wvb, Wob);

    gemm_qkv<<<dim3(64, 8, 3), 512, 0, stream>>>(xb, Wqb, Wkb, Wvb, Qb, Kb, Vtb);
    attn<<<dim3(64, 8), 512, 0, stream>>>(Qb, Kb, Vtb, ctxb);
    gemm_out<<<dim3(64, 8), 512, 0, stream>>>(ctxb, Wob, bo, out);
}

// Round 18
// 171.811 us; speedup vs baseline: 1.3160x; 1.0138x over previous
//
#include <hip/hip_runtime.h>

#define NH 16
#define HD 64
#define TSEQ 2048
#define DMODEL 1024

typedef __attribute__((ext_vector_type(8))) short short8;
typedef __attribute__((ext_vector_type(4))) float f32x4;

static __device__ __forceinline__ unsigned short f2bf(float f) {
    unsigned u = __builtin_bit_cast(unsigned, f);
    u += 0x7FFF + ((u >> 16) & 1);
    return (unsigned short)(u >> 16);
}

// packed f32x2 -> bf16x2 (low = a, high = b), single VALU op
static __device__ __forceinline__ unsigned cvtpk(float a, float b) {
    unsigned r;
    asm("v_cvt_pk_bf16_f32 %0, %1, %2" : "=v"(r) : "v"(a), "v"(b));
    return r;
}

// ---------------- cast f32 -> bf16 (vectorized) ----------------
__global__ __launch_bounds__(256) void cast_f32_bf16(const float* __restrict__ src,
                                                     unsigned short* __restrict__ dst, int n4) {
    int i = blockIdx.x * 256 + threadIdx.x;
    if (i >= n4) return;
    float4 v = reinterpret_cast<const float4*>(src)[i];
    ushort4 o;
    o.x = f2bf(v.x); o.y = f2bf(v.y); o.z = f2bf(v.z); o.w = f2bf(v.w);
    reinterpret_cast<ushort4*>(dst)[i] = o;
}

__global__ __launch_bounds__(256) void cast_weights(const float* __restrict__ Wq,
                                                    const float* __restrict__ Wk,
                                                    const float* __restrict__ Wv,
                                                    const float* __restrict__ Wo,
                                                    unsigned short* __restrict__ dq,
                                                    unsigned short* __restrict__ dk,
                                                    unsigned short* __restrict__ dv,
                                                    unsigned short* __restrict__ dwo) {
    int g = blockIdx.x >> 10;
    int i = (blockIdx.x & 1023) * 256 + threadIdx.x;
    const float* s = (g == 0) ? Wq : (g == 1) ? Wk : (g == 2) ? Wv : Wo;
    unsigned short* d = (g == 0) ? dq : (g == 1) ? dk : (g == 2) ? dv : dwo;
    float4 v = reinterpret_cast<const float4*>(s)[i];
    ushort4 o;
    o.x = f2bf(v.x); o.y = f2bf(v.y); o.z = f2bf(v.z); o.w = f2bf(v.w);
    reinterpret_cast<ushort4*>(d)[i] = o;
}

// ============ 256x128 GEMM mainloop: 512 threads, 3-ring, counted vmcnt ============
// (r12 verbatim — best measured GEMM config; r17's BM=128 regressed)
static __device__ __forceinline__ void gemm256_mainloop(
    const unsigned short* __restrict__ A, const unsigned short* __restrict__ Bt,
    int m0, int n0, unsigned short* As, unsigned short* Bs, f32x4 acc[4][4]) {
    const int tid = threadIdx.x, lane = tid & 63, w = tid >> 6;
    const int wr = w >> 1, wc = w & 1;      // 4M x 2N
    const int lg = lane >> 4, ll = lane & 15;
    const int strow = tid >> 2;             // 0..127
    const int su = tid & 3;                 // 16B unit within 64B row
    const int rx = ll & 3;                  // read-side XOR (== row&3 of frag rows)

    const f32x4 zero = {0.f, 0.f, 0.f, 0.f};
#pragma unroll
    for (int i = 0; i < 4; i++)
#pragma unroll
        for (int j = 0; j < 4; j++) acc[i][j] = zero;

    auto stage = [&](int kt, int slot) {    // 3 loads/thread: 2 A + 1 B
#pragma unroll
        for (int s = 0; s < 2; ++s) {       // A rows 0..255
            int row = s * 128 + strow;
            int gcol = kt * 32 + ((su ^ (row & 3)) * 8);
            __builtin_amdgcn_global_load_lds(
                (const __attribute__((address_space(1))) void*)(A + (size_t)(m0 + row) * DMODEL + gcol),
                (__attribute__((address_space(3))) void*)(As + slot * 8192 + row * 32 + su * 8), 16, 0, 0);
        }
        {                                   // B rows 0..127
            int row = strow;
            int gcol = kt * 32 + ((su ^ (row & 3)) * 8);
            __builtin_amdgcn_global_load_lds(
                (const __attribute__((address_space(1))) void*)(Bt + (size_t)(n0 + row) * DMODEL + gcol),
                (__attribute__((address_space(3))) void*)(Bs + slot * 4096 + row * 32 + su * 8), 16, 0, 0);
        }
    };

    // prologue: tiles 0,1; wait tile0 (tile1's 3 loads stay in flight)
    stage(0, 0);
    stage(1, 1);
    asm volatile("s_waitcnt vmcnt(3)" ::: "memory");
    __builtin_amdgcn_s_barrier();
    __builtin_amdgcn_sched_barrier(0);

    int pb = 0;
#pragma unroll 1
    for (int kt = 0; kt < 32; ++kt) {
        short8 af[4], bf[4];
#pragma unroll
        for (int i = 0; i < 4; i++)
            af[i] = *(const short8*)(As + pb * 8192 + (wr * 64 + i * 16 + ll) * 32 + ((lg ^ rx) * 8));
#pragma unroll
        for (int j = 0; j < 4; j++)
            bf[j] = *(const short8*)(Bs + pb * 4096 + (wc * 64 + j * 16 + ll) * 32 + ((lg ^ rx) * 8));
        const int pn = (pb + 2 >= 3) ? (pb - 1) : (pb + 2);
        if (kt + 2 < 32) stage(kt + 2, pn);

        asm volatile("s_waitcnt lgkmcnt(0)" ::: "memory");
        __builtin_amdgcn_sched_barrier(0);
        __builtin_amdgcn_s_setprio(1);
#pragma unroll
        for (int i = 0; i < 4; i++)
#pragma unroll
            for (int j = 0; j < 4; j++)
                acc[i][j] = __builtin_amdgcn_mfma_f32_16x16x32_bf16(af[i], bf[j], acc[i][j], 0, 0, 0);
        __builtin_amdgcn_s_setprio(0);
        __builtin_amdgcn_sched_barrier(0);
        if (kt + 2 < 32) {
            asm volatile("s_waitcnt vmcnt(3)" ::: "memory");   // kt+1 landed; kt+2 in flight
        } else {
            asm volatile("s_waitcnt vmcnt(0)" ::: "memory");   // tail drain
        }
        __builtin_amdgcn_s_barrier();
        __builtin_amdgcn_sched_barrier(0);
        pb = (pb + 1 >= 3) ? 0 : (pb + 1);
    }
}

// ---------------- QKV projection ----------------
#define QSCALE 0.180336880f
__global__ __launch_bounds__(512) void gemm_qkv(const unsigned short* __restrict__ xb,
                                                const unsigned short* __restrict__ Wqb,
                                                const unsigned short* __restrict__ Wkb,
                                                const unsigned short* __restrict__ Wvb,
                                                unsigned short* __restrict__ Q,
                                                unsigned short* __restrict__ K,
                                                unsigned short* __restrict__ Vt) {
    __shared__ __attribute__((aligned(16))) unsigned short As[3 * 256 * 32];
    __shared__ __attribute__((aligned(16))) unsigned short Bs[3 * 128 * 32];
    const int m0 = blockIdx.x * 256;
    const int n0 = blockIdx.y * 128;
    const int z = blockIdx.z;
    const unsigned short* Bt = (z == 0) ? Wqb : ((z == 1) ? Wkb : Wvb);
    unsigned short* out = (z == 0) ? Q : ((z == 1) ? K : Vt);

    f32x4 acc[4][4];
    gemm256_mainloop(xb, Bt, m0, n0, As, Bs, acc);

    const int lane = threadIdx.x & 63, w = threadIdx.x >> 6;
    const int wr = w >> 1, wc = w & 1;
    const int lg = lane >> 4, ll = lane & 15;
    const float sc = (z == 0) ? QSCALE : 1.0f;
    if (z == 2) {
#pragma unroll
        for (int i = 0; i < 4; i++)
#pragma unroll
            for (int j = 0; j < 4; j++) {
                int row0 = m0 + wr * 64 + i * 16 + lg * 4;      // aligned to 4
                int col = n0 + wc * 64 + j * 16 + ll;
                int b = row0 >> 11, t0 = row0 & 2047;
                int h = col >> 6, d = col & 63;
                ushort4 v4;
                v4.x = f2bf(acc[i][j][0]); v4.y = f2bf(acc[i][j][1]);
                v4.z = f2bf(acc[i][j][2]); v4.w = f2bf(acc[i][j][3]);
                *(ushort4*)&Vt[(((size_t)(b * NH + h)) * HD + d) * TSEQ + t0] = v4;
            }
    } else {
#pragma unroll
        for (int i = 0; i < 4; i++)
#pragma unroll
            for (int j = 0; j < 4; j++)
#pragma unroll
                for (int r = 0; r < 4; r++) {
                    int row = m0 + wr * 64 + i * 16 + lg * 4 + r;   // b*2048 + t
                    int col = n0 + wc * 64 + j * 16 + ll;           // h*64 + d
                    int b = row >> 11, t = row & 2047;
                    int h = col >> 6, d = col & 63;
                    out[(((size_t)(b * NH + h)) * TSEQ + t) * HD + d] = f2bf(acc[i][j][r] * sc);
                }
    }
}

// ---------------- output projection ----------------
__global__ __launch_bounds__(512) void gemm_out(const unsigned short* __restrict__ ctx,
                                                const unsigned short* __restrict__ Wob,
                                                const float* __restrict__ bo,
                                                float* __restrict__ out) {
    __shared__ __attribute__((aligned(16))) unsigned short As[3 * 256 * 32];
    __shared__ __attribute__((aligned(16))) unsigned short Bs[3 * 128 * 32];
    const int m0 = blockIdx.x * 256;
    const int n0 = blockIdx.y * 128;

    f32x4 acc[4][4];
    gemm256_mainloop(ctx, Wob, m0, n0, As, Bs, acc);

    const int lane = threadIdx.x & 63, w = threadIdx.x >> 6;
    const int wr = w >> 1, wc = w & 1;
    const int lg = lane >> 4, ll = lane & 15;
#pragma unroll
    for (int i = 0; i < 4; i++)
#pragma unroll
        for (int j = 0; j < 4; j++) {
            int col = n0 + wc * 64 + j * 16 + ll;
            float bias = bo[col];
#pragma unroll
            for (int r = 0; r < 4; r++) {
                int row = m0 + wr * 64 + i * 16 + lg * 4 + r;
                out[(size_t)row * DMODEL + col] = acc[i][j][r] + bias;
            }
        }
}

// ---------------- flash attention (causal), PAIRED q-tiles, 1 block/CU ----------------
// r18: each block processes TWO q-tiles sequentially — pair (7-y, y) —
// so every block does a uniform 36 KV-tile iterations. Grid 64 x 4 = 256
// blocks = exactly 1 per CU: each block is SOLE TENANT of its CU's DS pipe
// (r12's wall = 2 blocks/CU sharing one DS pipe: ~208KB LDS traffic x 32
// tiles x 2 blocks ~ 157k cyc ~ 65us, matching the measured 72). Uniform
// cost also eliminates the drain (r12 occupancy 20% = idle CUs).
// Inner body = r12's proven structure (2 barriers/tile, reg-staged
// prefetch, S^T mfma(K,Q), in-reg softmax, cvt_pk P, O^T = mfma(Vt,P)).
__global__ __launch_bounds__(512) void attn(const unsigned short* __restrict__ Qg,
                                            const unsigned short* __restrict__ Kg,
                                            const unsigned short* __restrict__ Vg,
                                            unsigned short* __restrict__ ctx) {
    __shared__ __attribute__((aligned(16))) unsigned short Ks[64][72];
    __shared__ __attribute__((aligned(16))) unsigned short Vs[64][72];
    __shared__ __attribute__((aligned(16))) unsigned short Pl[256][76];

    const int tid = threadIdx.x, lane = tid & 63, w = tid >> 6;   // w = 0..7
    const int wq = w * 32;
    const int lg = lane >> 4;
    const int ll = lane & 15;
    const int bh = blockIdx.x;
    const unsigned short* Qh = Qg + (size_t)bh * TSEQ * HD;
    const unsigned short* Kh = Kg + (size_t)bh * TSEQ * HD;
    const unsigned short* Vh = Vg + (size_t)bh * HD * TSEQ;
    const int b = bh >> 4, h = bh & 15;
    const int sr = tid >> 3;           // 0..63
    const int sc = (tid & 7) * 8;      // 0..56
    const f32x4 zerov = {0.f, 0.f, 0.f, 0.f};

#pragma unroll 1
    for (int ph = 0; ph < 2; ph++) {
        // pair (heavy, light): uniform 36 total iterations per block
        const int ty = (ph == 0) ? (7 - blockIdx.y) : blockIdx.y;
        const int q0 = ty * 256;

        short8 qf[2][2];
#pragma unroll
        for (int rb = 0; rb < 2; rb++)
#pragma unroll
            for (int ks = 0; ks < 2; ks++)
                qf[rb][ks] = *(const short8*)(Qh + (size_t)(q0 + wq + rb * 16 + ll) * HD + ks * 32 + lg * 8);

        float mrun[2] = {-1e30f, -1e30f}, lrun[2] = {0.f, 0.f};
        f32x4 o_t[2][4];
#pragma unroll
        for (int rb = 0; rb < 2; rb++)
#pragma unroll
            for (int db = 0; db < 4; db++) o_t[rb][db] = zerov;

        short8 kreg, vreg;
        kreg = *(const short8*)(Kh + (size_t)sr * HD + sc);
        vreg = *(const short8*)(Vh + (size_t)sr * TSEQ + sc);

        const int nkv = q0 / 64 + 4;
        for (int kt = 0; kt < nkv; kt++) {
            const int kv0 = kt * 64;
            __builtin_amdgcn_s_barrier();     // prev tile's (or prev phase's) readers done
            __builtin_amdgcn_sched_barrier(0);
            *(short8*)&Ks[sr][sc] = kreg;
            *(short8*)&Vs[sr][sc] = vreg;
            if (kt + 1 < nkv) {
                const int nv0 = kv0 + 64;
                kreg = *(const short8*)(Kh + (size_t)(nv0 + sr) * HD + sc);
                vreg = *(const short8*)(Vh + (size_t)sr * TSEQ + nv0 + sc);
            }
            __builtin_amdgcn_sched_barrier(0);
            asm volatile("s_waitcnt lgkmcnt(0)" ::: "memory");
            __builtin_amdgcn_s_barrier();
            __builtin_amdgcn_sched_barrier(0);

            if (kv0 > q0 + wq + 31) continue;   // fully masked for this wave

            short8 af0[4], af1[4];
#pragma unroll
            for (int cb = 0; cb < 4; cb++) {
                af0[cb] = *(const short8*)&Ks[cb * 16 + ll][lg * 8];
                af1[cb] = *(const short8*)&Ks[cb * 16 + ll][32 + lg * 8];
            }
            f32x4 st[2][4];
#pragma unroll
            for (int rb = 0; rb < 2; rb++)
#pragma unroll
                for (int cb = 0; cb < 4; cb++)
                    st[rb][cb] = __builtin_amdgcn_mfma_f32_16x16x32_bf16(af0[cb], qf[rb][0], zerov, 0, 0, 0);
#pragma unroll
            for (int rb = 0; rb < 2; rb++)
#pragma unroll
                for (int cb = 0; cb < 4; cb++)
                    st[rb][cb] = __builtin_amdgcn_mfma_f32_16x16x32_bf16(af1[cb], qf[rb][1], st[rb][cb], 0, 0, 0);

            if (kv0 + 63 > q0 + wq) {
#pragma unroll
                for (int rb = 0; rb < 2; rb++)
#pragma unroll
                    for (int cb = 0; cb < 4; cb++)
#pragma unroll
                        for (int r = 0; r < 4; r++) {
                            int kvl = cb * 16 + lg * 4 + r;
                            int ql = wq + rb * 16 + ll;
                            if (kv0 + kvl > q0 + ql) st[rb][cb][r] = -1e30f;
                        }
            }

            float mx[2];
#pragma unroll
            for (int rb = 0; rb < 2; rb++) {
                float a0 = fmaxf(fmaxf(st[rb][0][0], st[rb][0][1]), fmaxf(st[rb][0][2], st[rb][0][3]));
                float a1 = fmaxf(fmaxf(st[rb][1][0], st[rb][1][1]), fmaxf(st[rb][1][2], st[rb][1][3]));
                float a2 = fmaxf(fmaxf(st[rb][2][0], st[rb][2][1]), fmaxf(st[rb][2][2], st[rb][2][3]));
                float a3 = fmaxf(fmaxf(st[rb][3][0], st[rb][3][1]), fmaxf(st[rb][3][2], st[rb][3][3]));
                float m = fmaxf(fmaxf(a0, a1), fmaxf(a2, a3));
                m = fmaxf(m, __shfl_xor(m, 16));
                m = fmaxf(m, __shfl_xor(m, 32));
                mx[rb] = m;
            }
            float need = fmaxf(mx[0] - mrun[0], mx[1] - mrun[1]);
            if (__any(need > 8.f)) {
#pragma unroll
                for (int rb = 0; rb < 2; rb++) {
                    float mold = mrun[rb];
                    float mn = fmaxf(mold, mx[rb]);
                    float rs = __builtin_amdgcn_exp2f(mold - mn);
                    mrun[rb] = mn;
                    lrun[rb] *= rs;
#pragma unroll
                    for (int db = 0; db < 4; db++)
#pragma unroll
                        for (int r = 0; r < 4; r++) o_t[rb][db][r] *= rs;
                }
            }
#pragma unroll
            for (int rb = 0; rb < 2; rb++) {
                float sum = 0.f;
#pragma unroll
                for (int cb = 0; cb < 4; cb++) {
                    float p0 = __builtin_amdgcn_exp2f(st[rb][cb][0] - mrun[rb]);
                    float p1 = __builtin_amdgcn_exp2f(st[rb][cb][1] - mrun[rb]);
                    float p2 = __builtin_amdgcn_exp2f(st[rb][cb][2] - mrun[rb]);
                    float p3 = __builtin_amdgcn_exp2f(st[rb][cb][3] - mrun[rb]);
                    sum += (p0 + p1) + (p2 + p3);
                    uint2 pw;
                    pw.x = cvtpk(p0, p1);
                    pw.y = cvtpk(p2, p3);
                    *(uint2*)&Pl[wq + rb * 16 + ll][cb * 16 + lg * 4] = pw;
                }
                sum += __shfl_xor(sum, 16);
                sum += __shfl_xor(sum, 32);
                lrun[rb] += sum;
            }
            asm volatile("s_waitcnt lgkmcnt(0)" ::: "memory");
            __builtin_amdgcn_sched_barrier(0);

#pragma unroll
            for (int ks = 0; ks < 2; ks++) {
                short8 pa[2], va[4];
#pragma unroll
                for (int rb = 0; rb < 2; rb++)
                    pa[rb] = *(const short8*)&Pl[wq + rb * 16 + ll][ks * 32 + lg * 8];
#pragma unroll
                for (int db = 0; db < 4; db++)
                    va[db] = *(const short8*)&Vs[db * 16 + ll][ks * 32 + lg * 8];
#pragma unroll
                for (int rb = 0; rb < 2; rb++)
#pragma unroll
                    for (int db = 0; db < 4; db++)
                        o_t[rb][db] = __builtin_amdgcn_mfma_f32_16x16x32_bf16(va[db], pa[rb], o_t[rb][db], 0, 0, 0);
            }
        }

        // epilogue for this phase: scale by 1/l, transpose via wave-private Pl, store
#pragma unroll
        for (int rb = 0; rb < 2; rb++) {
            float linv = 1.f / lrun[rb];
#pragma unroll
            for (int db = 0; db < 4; db++) {
                uint2 pw;
                pw.x = cvtpk(o_t[rb][db][0] * linv, o_t[rb][db][1] * linv);
                pw.y = cvtpk(o_t[rb][db][2] * linv, o_t[rb][db][3] * linv);
                *(uint2*)&Pl[wq + rb * 16 + ll][db * 16 + lg * 4] = pw;
            }
        }
        asm volatile("s_waitcnt lgkmcnt(0)" ::: "memory");
        __builtin_amdgcn_sched_barrier(0);
#pragma unroll
        for (int rb = 0; rb < 2; rb++)
#pragma unroll
            for (int half = 0; half < 2; half++) {
                short8 v = *(const short8*)&Pl[wq + rb * 16 + ll][half * 32 + lg * 8];
                size_t row = (size_t)(b * TSEQ + q0 + wq + rb * 16 + ll);
                *(short8*)(ctx + (row * NH + h) * HD + half * 32 + lg * 8) = v;
            }
    }
}

extern "C" void kernel_launch(void* const* d_in, const int* in_sizes, int n_in,
                              void* d_out, int out_size, void* d_ws, size_t ws_size,
                              hipStream_t stream) {
    const float* x  = (const float*)d_in[0];
    const float* Wq = (const float*)d_in[1];
    const float* Wk = (const float*)d_in[2];
    const float* Wv = (const float*)d_in[3];
    const float* Wo = (const float*)d_in[4];
    const float* bo = (const float*)d_in[5];
    float* out = (float*)d_out;

    char* ws = (char*)d_ws;
    unsigned short* xb   = (unsigned short*)(ws);             // 16,777,216 B
    unsigned short* Wqb  = (unsigned short*)(ws + 16777216);
    unsigned short* Wkb  = (unsigned short*)(ws + 18874368);
    unsigned short* Wvb  = (unsigned short*)(ws + 20971520);
    unsigned short* Wob  = (unsigned short*)(ws + 23068672);
    unsigned short* Qb   = (unsigned short*)(ws + 25165824);  // [B,H,T,hd] bf16 (pre-scaled)
    unsigned short* Kb   = (unsigned short*)(ws + 41943040);  // [B,H,T,hd]
    unsigned short* Vtb  = (unsigned short*)(ws + 58720256);  // [B,H,hd,T]
    unsigned short* ctxb = (unsigned short*)(ws + 75497472);  // [B,T,H,hd]

    cast_f32_bf16<<<8192, 256, 0, stream>>>(x, xb, 2097152);
    cast_weights<<<4096, 256, 0, stream>>>(Wq, Wk, Wv, Wo, Wqb, Wkb, Wvb, Wob);

    gemm_qkv<<<dim3(32, 8, 3), 512, 0, stream>>>(xb, Wqb, Wkb, Wvb, Qb, Kb, Vtb);
    attn<<<dim3(64, 4), 512, 0, stream>>>(Qb, Kb, Vtb, ctxb);
    gemm_out<<<dim3(32, 8), 512, 0, stream>>>(ctxb, Wob, bo, out);
}

// Round 19
// 169.774 us; speedup vs baseline: 1.3318x; 1.0120x over previous
//
#include <hip/hip_runtime.h>

#define NH 16
#define HD 64
#define TSEQ 2048
#define DMODEL 1024

typedef __attribute__((ext_vector_type(8))) short short8;
typedef __attribute__((ext_vector_type(4))) float f32x4;

static __device__ __forceinline__ unsigned short f2bf(float f) {
    unsigned u = __builtin_bit_cast(unsigned, f);
    u += 0x7FFF + ((u >> 16) & 1);
    return (unsigned short)(u >> 16);
}

// packed f32x2 -> bf16x2 (low = a, high = b), single VALU op
static __device__ __forceinline__ unsigned cvtpk(float a, float b) {
    unsigned r;
    asm("v_cvt_pk_bf16_f32 %0, %1, %2" : "=v"(r) : "v"(a), "v"(b));
    return r;
}

// ---------------- cast f32 -> bf16 (vectorized) ----------------
__global__ __launch_bounds__(256) void cast_f32_bf16(const float* __restrict__ src,
                                                     unsigned short* __restrict__ dst, int n4) {
    int i = blockIdx.x * 256 + threadIdx.x;
    if (i >= n4) return;
    float4 v = reinterpret_cast<const float4*>(src)[i];
    ushort4 o;
    o.x = f2bf(v.x); o.y = f2bf(v.y); o.z = f2bf(v.z); o.w = f2bf(v.w);
    reinterpret_cast<ushort4*>(dst)[i] = o;
}

__global__ __launch_bounds__(256) void cast_weights(const float* __restrict__ Wq,
                                                    const float* __restrict__ Wk,
                                                    const float* __restrict__ Wv,
                                                    const float* __restrict__ Wo,
                                                    unsigned short* __restrict__ dq,
                                                    unsigned short* __restrict__ dk,
                                                    unsigned short* __restrict__ dv,
                                                    unsigned short* __restrict__ dwo) {
    int g = blockIdx.x >> 10;
    int i = (blockIdx.x & 1023) * 256 + threadIdx.x;
    const float* s = (g == 0) ? Wq : (g == 1) ? Wk : (g == 2) ? Wv : Wo;
    unsigned short* d = (g == 0) ? dq : (g == 1) ? dk : (g == 2) ? dv : dwo;
    float4 v = reinterpret_cast<const float4*>(s)[i];
    ushort4 o;
    o.x = f2bf(v.x); o.y = f2bf(v.y); o.z = f2bf(v.z); o.w = f2bf(v.w);
    reinterpret_cast<ushort4*>(d)[i] = o;
}

// ============ 256x128 GEMM mainloop: 512 threads, 3-ring, counted vmcnt ============
// (r12 verbatim — best measured GEMM config)
static __device__ __forceinline__ void gemm256_mainloop(
    const unsigned short* __restrict__ A, const unsigned short* __restrict__ Bt,
    int m0, int n0, unsigned short* As, unsigned short* Bs, f32x4 acc[4][4]) {
    const int tid = threadIdx.x, lane = tid & 63, w = tid >> 6;
    const int wr = w >> 1, wc = w & 1;      // 4M x 2N
    const int lg = lane >> 4, ll = lane & 15;
    const int strow = tid >> 2;             // 0..127
    const int su = tid & 3;                 // 16B unit within 64B row
    const int rx = ll & 3;                  // read-side XOR (== row&3 of frag rows)

    const f32x4 zero = {0.f, 0.f, 0.f, 0.f};
#pragma unroll
    for (int i = 0; i < 4; i++)
#pragma unroll
        for (int j = 0; j < 4; j++) acc[i][j] = zero;

    auto stage = [&](int kt, int slot) {    // 3 loads/thread: 2 A + 1 B
#pragma unroll
        for (int s = 0; s < 2; ++s) {       // A rows 0..255
            int row = s * 128 + strow;
            int gcol = kt * 32 + ((su ^ (row & 3)) * 8);
            __builtin_amdgcn_global_load_lds(
                (const __attribute__((address_space(1))) void*)(A + (size_t)(m0 + row) * DMODEL + gcol),
                (__attribute__((address_space(3))) void*)(As + slot * 8192 + row * 32 + su * 8), 16, 0, 0);
        }
        {                                   // B rows 0..127
            int row = strow;
            int gcol = kt * 32 + ((su ^ (row & 3)) * 8);
            __builtin_amdgcn_global_load_lds(
                (const __attribute__((address_space(1))) void*)(Bt + (size_t)(n0 + row) * DMODEL + gcol),
                (__attribute__((address_space(3))) void*)(Bs + slot * 4096 + row * 32 + su * 8), 16, 0, 0);
        }
    };

    // prologue: tiles 0,1; wait tile0 (tile1's 3 loads stay in flight)
    stage(0, 0);
    stage(1, 1);
    asm volatile("s_waitcnt vmcnt(3)" ::: "memory");
    __builtin_amdgcn_s_barrier();
    __builtin_amdgcn_sched_barrier(0);

    int pb = 0;
#pragma unroll 1
    for (int kt = 0; kt < 32; ++kt) {
        short8 af[4], bf[4];
#pragma unroll
        for (int i = 0; i < 4; i++)
            af[i] = *(const short8*)(As + pb * 8192 + (wr * 64 + i * 16 + ll) * 32 + ((lg ^ rx) * 8));
#pragma unroll
        for (int j = 0; j < 4; j++)
            bf[j] = *(const short8*)(Bs + pb * 4096 + (wc * 64 + j * 16 + ll) * 32 + ((lg ^ rx) * 8));
        const int pn = (pb + 2 >= 3) ? (pb - 1) : (pb + 2);
        if (kt + 2 < 32) stage(kt + 2, pn);

        asm volatile("s_waitcnt lgkmcnt(0)" ::: "memory");
        __builtin_amdgcn_sched_barrier(0);
        __builtin_amdgcn_s_setprio(1);
#pragma unroll
        for (int i = 0; i < 4; i++)
#pragma unroll
            for (int j = 0; j < 4; j++)
                acc[i][j] = __builtin_amdgcn_mfma_f32_16x16x32_bf16(af[i], bf[j], acc[i][j], 0, 0, 0);
        __builtin_amdgcn_s_setprio(0);
        __builtin_amdgcn_sched_barrier(0);
        if (kt + 2 < 32) {
            asm volatile("s_waitcnt vmcnt(3)" ::: "memory");   // kt+1 landed; kt+2 in flight
        } else {
            asm volatile("s_waitcnt vmcnt(0)" ::: "memory");   // tail drain
        }
        __builtin_amdgcn_s_barrier();
        __builtin_amdgcn_sched_barrier(0);
        pb = (pb + 1 >= 3) ? 0 : (pb + 1);
    }
}

// ---------------- QKV projection ----------------
#define QSCALE 0.180336880f
__global__ __launch_bounds__(512) void gemm_qkv(const unsigned short* __restrict__ xb,
                                                const unsigned short* __restrict__ Wqb,
                                                const unsigned short* __restrict__ Wkb,
                                                const unsigned short* __restrict__ Wvb,
                                                unsigned short* __restrict__ Q,
                                                unsigned short* __restrict__ K,
                                                unsigned short* __restrict__ Vt) {
    __shared__ __attribute__((aligned(16))) unsigned short As[3 * 256 * 32];
    __shared__ __attribute__((aligned(16))) unsigned short Bs[3 * 128 * 32];
    const int m0 = blockIdx.x * 256;
    const int n0 = blockIdx.y * 128;
    const int z = blockIdx.z;
    const unsigned short* Bt = (z == 0) ? Wqb : ((z == 1) ? Wkb : Wvb);
    unsigned short* out = (z == 0) ? Q : ((z == 1) ? K : Vt);

    f32x4 acc[4][4];
    gemm256_mainloop(xb, Bt, m0, n0, As, Bs, acc);

    const int lane = threadIdx.x & 63, w = threadIdx.x >> 6;
    const int wr = w >> 1, wc = w & 1;
    const int lg = lane >> 4, ll = lane & 15;
    const float sc = (z == 0) ? QSCALE : 1.0f;
    if (z == 2) {
#pragma unroll
        for (int i = 0; i < 4; i++)
#pragma unroll
            for (int j = 0; j < 4; j++) {
                int row0 = m0 + wr * 64 + i * 16 + lg * 4;      // aligned to 4
                int col = n0 + wc * 64 + j * 16 + ll;
                int b = row0 >> 11, t0 = row0 & 2047;
                int h = col >> 6, d = col & 63;
                ushort4 v4;
                v4.x = f2bf(acc[i][j][0]); v4.y = f2bf(acc[i][j][1]);
                v4.z = f2bf(acc[i][j][2]); v4.w = f2bf(acc[i][j][3]);
                *(ushort4*)&Vt[(((size_t)(b * NH + h)) * HD + d) * TSEQ + t0] = v4;
            }
    } else {
#pragma unroll
        for (int i = 0; i < 4; i++)
#pragma unroll
            for (int j = 0; j < 4; j++)
#pragma unroll
                for (int r = 0; r < 4; r++) {
                    int row = m0 + wr * 64 + i * 16 + lg * 4 + r;   // b*2048 + t
                    int col = n0 + wc * 64 + j * 16 + ll;           // h*64 + d
                    int b = row >> 11, t = row & 2047;
                    int h = col >> 6, d = col & 63;
                    out[(((size_t)(b * NH + h)) * TSEQ + t) * HD + d] = f2bf(acc[i][j][r] * sc);
                }
    }
}

// ---------------- output projection ----------------
__global__ __launch_bounds__(512) void gemm_out(const unsigned short* __restrict__ ctx,
                                                const unsigned short* __restrict__ Wob,
                                                const float* __restrict__ bo,
                                                float* __restrict__ out) {
    __shared__ __attribute__((aligned(16))) unsigned short As[3 * 256 * 32];
    __shared__ __attribute__((aligned(16))) unsigned short Bs[3 * 128 * 32];
    const int m0 = blockIdx.x * 256;
    const int n0 = blockIdx.y * 128;

    f32x4 acc[4][4];
    gemm256_mainloop(ctx, Wob, m0, n0, As, Bs, acc);

    const int lane = threadIdx.x & 63, w = threadIdx.x >> 6;
    const int wr = w >> 1, wc = w & 1;
    const int lg = lane >> 4, ll = lane & 15;
#pragma unroll
    for (int i = 0; i < 4; i++)
#pragma unroll
        for (int j = 0; j < 4; j++) {
            int col = n0 + wc * 64 + j * 16 + ll;
            float bias = bo[col];
#pragma unroll
            for (int r = 0; r < 4; r++) {
                int row = m0 + wr * 64 + i * 16 + lg * 4 + r;
                out[(size_t)row * DMODEL + col] = acc[i][j][r] + bias;
            }
        }
}

// ---------------- flash attention (causal), Q-tile 256, KV-ROUND 128, 8 waves ----------------
// r19: KVBLK 64 -> 128. One staging round covers TWO 64-row KV sub-tiles
// computed back-to-back from LDS with NO barrier between them (LDS reads
// only). Barriers, staging rounds, and their lgkm drains halve per kv-row;
// the compute chain between barriers doubles so waves can slip phase-wise
// within a round (r12-r18 invariance diagnosis: lockstep phase sequence =
// the cost floor; fixed per-tile latencies paid 36x). Sub-tile body is
// r12's proven code. LDS = K 18,432 + V 17,408 + P 38,912 = 74,752 B ->
// same 2 blocks/CU as r12.
__global__ __launch_bounds__(512) void attn(const unsigned short* __restrict__ Qg,
                                            const unsigned short* __restrict__ Kg,
                                            const unsigned short* __restrict__ Vg,
                                            unsigned short* __restrict__ ctx) {
    __shared__ __attribute__((aligned(16))) unsigned short Ks[128][72];
    __shared__ __attribute__((aligned(16))) unsigned short Vs[64][136];
    __shared__ __attribute__((aligned(16))) unsigned short Pl[256][76];

    const int tid = threadIdx.x, lane = tid & 63, w = tid >> 6;   // w = 0..7
    const int wq = w * 32;
    const int lg = lane >> 4;
    const int ll = lane & 15;
    const int bh = blockIdx.x;
    const int q0 = (gridDim.y - 1 - blockIdx.y) * 256;   // heavy tiles first (LPT)
    const unsigned short* Qh = Qg + (size_t)bh * TSEQ * HD;
    const unsigned short* Kh = Kg + (size_t)bh * TSEQ * HD;
    const unsigned short* Vh = Vg + (size_t)bh * HD * TSEQ;

    short8 qf[2][2];
#pragma unroll
    for (int rb = 0; rb < 2; rb++)
#pragma unroll
        for (int ks = 0; ks < 2; ks++)
            qf[rb][ks] = *(const short8*)(Qh + (size_t)(q0 + wq + rb * 16 + ll) * HD + ks * 32 + lg * 8);

    float mrun[2] = {-1e30f, -1e30f}, lrun[2] = {0.f, 0.f};
    const f32x4 zerov = {0.f, 0.f, 0.f, 0.f};
    f32x4 o_t[2][4];
#pragma unroll
    for (int rb = 0; rb < 2; rb++)
#pragma unroll
        for (int db = 0; db < 4; db++) o_t[rb][db] = zerov;

    // staging for 128-row K round + 64x128 V round (4 loads/thread)
    const int kr = tid >> 3;            // 0..63 -> K rows kr, kr+64
    const int kc = (tid & 7) * 8;       // K col 0..56
    const int vd = tid >> 4;            // 0..31 -> V rows vd, vd+32
    const int vt = (tid & 15) * 8;      // V col 0..120
    short8 kreg0, kreg1, vreg0, vreg1;
    kreg0 = *(const short8*)(Kh + (size_t)kr * HD + kc);
    kreg1 = *(const short8*)(Kh + (size_t)(kr + 64) * HD + kc);
    vreg0 = *(const short8*)(Vh + (size_t)vd * TSEQ + vt);
    vreg1 = *(const short8*)(Vh + (size_t)(vd + 32) * TSEQ + vt);

    const int nrd = q0 / 128 + 2;       // 128-row rounds (q0 mult of 256 -> exact)
    for (int rd = 0; rd < nrd; rd++) {
        const int rv0 = rd * 128;
        __builtin_amdgcn_s_barrier();       // previous round's readers done
        __builtin_amdgcn_sched_barrier(0);
        *(short8*)&Ks[kr][kc] = kreg0;
        *(short8*)&Ks[kr + 64][kc] = kreg1;
        *(short8*)&Vs[vd][vt] = vreg0;
        *(short8*)&Vs[vd + 32][vt] = vreg1;
        if (rd + 1 < nrd) {                 // next round's loads stay in flight
            const int nv0 = rv0 + 128;
            kreg0 = *(const short8*)(Kh + (size_t)(nv0 + kr) * HD + kc);
            kreg1 = *(const short8*)(Kh + (size_t)(nv0 + kr + 64) * HD + kc);
            vreg0 = *(const short8*)(Vh + (size_t)vd * TSEQ + nv0 + vt);
            vreg1 = *(const short8*)(Vh + (size_t)(vd + 32) * TSEQ + nv0 + vt);
        }
        __builtin_amdgcn_sched_barrier(0);
        asm volatile("s_waitcnt lgkmcnt(0)" ::: "memory");
        __builtin_amdgcn_s_barrier();       // round visible
        __builtin_amdgcn_sched_barrier(0);

#pragma unroll 1
        for (int sub = 0; sub < 2; sub++) {
            const int kv0 = rv0 + sub * 64;
            if (kv0 > q0 + wq + 31) continue;   // fully masked for this wave

            short8 af0[4], af1[4];
#pragma unroll
            for (int cb = 0; cb < 4; cb++) {
                af0[cb] = *(const short8*)&Ks[sub * 64 + cb * 16 + ll][lg * 8];
                af1[cb] = *(const short8*)&Ks[sub * 64 + cb * 16 + ll][32 + lg * 8];
            }
            f32x4 st[2][4];
#pragma unroll
            for (int rb = 0; rb < 2; rb++)
#pragma unroll
                for (int cb = 0; cb < 4; cb++)
                    st[rb][cb] = __builtin_amdgcn_mfma_f32_16x16x32_bf16(af0[cb], qf[rb][0], zerov, 0, 0, 0);
#pragma unroll
            for (int rb = 0; rb < 2; rb++)
#pragma unroll
                for (int cb = 0; cb < 4; cb++)
                    st[rb][cb] = __builtin_amdgcn_mfma_f32_16x16x32_bf16(af1[cb], qf[rb][1], st[rb][cb], 0, 0, 0);

            if (kv0 + 63 > q0 + wq) {
#pragma unroll
                for (int rb = 0; rb < 2; rb++)
#pragma unroll
                    for (int cb = 0; cb < 4; cb++)
#pragma unroll
                        for (int r = 0; r < 4; r++) {
                            int kvl = cb * 16 + lg * 4 + r;
                            int ql = wq + rb * 16 + ll;
                            if (kv0 + kvl > q0 + ql) st[rb][cb][r] = -1e30f;
                        }
            }

            float mx[2];
#pragma unroll
            for (int rb = 0; rb < 2; rb++) {
                float a0 = fmaxf(fmaxf(st[rb][0][0], st[rb][0][1]), fmaxf(st[rb][0][2], st[rb][0][3]));
                float a1 = fmaxf(fmaxf(st[rb][1][0], st[rb][1][1]), fmaxf(st[rb][1][2], st[rb][1][3]));
                float a2 = fmaxf(fmaxf(st[rb][2][0], st[rb][2][1]), fmaxf(st[rb][2][2], st[rb][2][3]));
                float a3 = fmaxf(fmaxf(st[rb][3][0], st[rb][3][1]), fmaxf(st[rb][3][2], st[rb][3][3]));
                float m = fmaxf(fmaxf(a0, a1), fmaxf(a2, a3));
                m = fmaxf(m, __shfl_xor(m, 16));
                m = fmaxf(m, __shfl_xor(m, 32));
                mx[rb] = m;
            }
            float need = fmaxf(mx[0] - mrun[0], mx[1] - mrun[1]);
            if (__any(need > 8.f)) {
#pragma unroll
                for (int rb = 0; rb < 2; rb++) {
                    float mold = mrun[rb];
                    float mn = fmaxf(mold, mx[rb]);
                    float rs = __builtin_amdgcn_exp2f(mold - mn);
                    mrun[rb] = mn;
                    lrun[rb] *= rs;
#pragma unroll
                    for (int db = 0; db < 4; db++)
#pragma unroll
                        for (int r = 0; r < 4; r++) o_t[rb][db][r] *= rs;
                }
            }
#pragma unroll
            for (int rb = 0; rb < 2; rb++) {
                float sum = 0.f;
#pragma unroll
                for (int cb = 0; cb < 4; cb++) {
                    float p0 = __builtin_amdgcn_exp2f(st[rb][cb][0] - mrun[rb]);
                    float p1 = __builtin_amdgcn_exp2f(st[rb][cb][1] - mrun[rb]);
                    float p2 = __builtin_amdgcn_exp2f(st[rb][cb][2] - mrun[rb]);
                    float p3 = __builtin_amdgcn_exp2f(st[rb][cb][3] - mrun[rb]);
                    sum += (p0 + p1) + (p2 + p3);
                    uint2 pw;
                    pw.x = cvtpk(p0, p1);
                    pw.y = cvtpk(p2, p3);
                    *(uint2*)&Pl[wq + rb * 16 + ll][cb * 16 + lg * 4] = pw;
                }
                sum += __shfl_xor(sum, 16);
                sum += __shfl_xor(sum, 32);
                lrun[rb] += sum;
            }
            asm volatile("s_waitcnt lgkmcnt(0)" ::: "memory");
            __builtin_amdgcn_sched_barrier(0);

#pragma unroll
            for (int ks = 0; ks < 2; ks++) {
                short8 pa[2], va[4];
#pragma unroll
                for (int rb = 0; rb < 2; rb++)
                    pa[rb] = *(const short8*)&Pl[wq + rb * 16 + ll][ks * 32 + lg * 8];
#pragma unroll
                for (int db = 0; db < 4; db++)
                    va[db] = *(const short8*)&Vs[db * 16 + ll][sub * 64 + ks * 32 + lg * 8];
#pragma unroll
                for (int rb = 0; rb < 2; rb++)
#pragma unroll
                    for (int db = 0; db < 4; db++)
                        o_t[rb][db] = __builtin_amdgcn_mfma_f32_16x16x32_bf16(va[db], pa[rb], o_t[rb][db], 0, 0, 0);
            }
        }
    }

    const int b = bh >> 4, h = bh & 15;
#pragma unroll
    for (int rb = 0; rb < 2; rb++) {
        float linv = 1.f / lrun[rb];
#pragma unroll
        for (int db = 0; db < 4; db++) {
            uint2 pw;
            pw.x = cvtpk(o_t[rb][db][0] * linv, o_t[rb][db][1] * linv);
            pw.y = cvtpk(o_t[rb][db][2] * linv, o_t[rb][db][3] * linv);
            *(uint2*)&Pl[wq + rb * 16 + ll][db * 16 + lg * 4] = pw;
        }
    }
    asm volatile("s_waitcnt lgkmcnt(0)" ::: "memory");
    __builtin_amdgcn_sched_barrier(0);
#pragma unroll
    for (int rb = 0; rb < 2; rb++)
#pragma unroll
        for (int half = 0; half < 2; half++) {
            short8 v = *(const short8*)&Pl[wq + rb * 16 + ll][half * 32 + lg * 8];
            size_t row = (size_t)(b * TSEQ + q0 + wq + rb * 16 + ll);
            *(short8*)(ctx + (row * NH + h) * HD + half * 32 + lg * 8) = v;
        }
}

extern "C" void kernel_launch(void* const* d_in, const int* in_sizes, int n_in,
                              void* d_out, int out_size, void* d_ws, size_t ws_size,
                              hipStream_t stream) {
    const float* x  = (const float*)d_in[0];
    const float* Wq = (const float*)d_in[1];
    const float* Wk = (const float*)d_in[2];
    const float* Wv = (const float*)d_in[3];
    const float* Wo = (const float*)d_in[4];
    const float* bo = (const float*)d_in[5];
    float* out = (float*)d_out;

    char* ws = (char*)d_ws;
    unsigned short* xb   = (unsigned short*)(ws);             // 16,777,216 B
    unsigned short* Wqb  = (unsigned short*)(ws + 16777216);
    unsigned short* Wkb  = (unsigned short*)(ws + 18874368);
    unsigned short* Wvb  = (unsigned short*)(ws + 20971520);
    unsigned short* Wob  = (unsigned short*)(ws + 23068672);
    unsigned short* Qb   = (unsigned short*)(ws + 25165824);  // [B,H,T,hd] bf16 (pre-scaled)
    unsigned short* Kb   = (unsigned short*)(ws + 41943040);  // [B,H,T,hd]
    unsigned short* Vtb  = (unsigned short*)(ws + 58720256);  // [B,H,hd,T]
    unsigned short* ctxb = (unsigned short*)(ws + 75497472);  // [B,T,H,hd]

    cast_f32_bf16<<<8192, 256, 0, stream>>>(x, xb, 2097152);
    cast_weights<<<4096, 256, 0, stream>>>(Wq, Wk, Wv, Wo, Wqb, Wkb, Wvb, Wob);

    gemm_qkv<<<dim3(32, 8, 3), 512, 0, stream>>>(xb, Wqb, Wkb, Wvb, Qb, Kb, Vtb);
    attn<<<dim3(64, 8), 512, 0, stream>>>(Qb, Kb, Vtb, ctxb);
    gemm_out<<<dim3(32, 8), 512, 0, stream>>>(ctxb, Wob, bo, out);
}